// Round 1
// baseline (210.075 us; speedup 1.0000x reference)
//
#include <hip/hip_runtime.h>

#define NRAYS 8192
#define NS    256
#define HID   64

__global__ __launch_bounds__(256) void vr_kernel(
    const float* __restrict__ ray_start,
    const float* __restrict__ ray_dir,
    const float* __restrict__ sampled_depth,
    const float* __restrict__ sampled_dists,
    const int*   __restrict__ sampled_idx,
    const float* __restrict__ W1,
    const float* __restrict__ b1,
    const float* __restrict__ w_sigma,
    const float* __restrict__ W_rgb,
    const float* __restrict__ W_dir,
    const float* __restrict__ b_rgb,
    float* __restrict__ out)
{
    // Packed weight tables: per hidden unit h,
    //   sWA[h] = {W1[0][h], W1[1][h], W1[2][h], b1[h]}
    //   sWB[h] = {w_sigma[h], W_rgb[h][0], W_rgb[h][1], W_rgb[h][2]}
    __shared__ float4 sWA[HID];
    __shared__ float4 sWB[HID];
    __shared__ float  sWd[12];       // W_dir (9) + b_rgb (3)
    __shared__ float  waveSum[4];
    __shared__ float  red[4][5];

    const int t = threadIdx.x;
    if (t < HID) {
        sWA[t] = make_float4(W1[t], W1[HID + t], W1[2*HID + t], b1[t]);
        sWB[t] = make_float4(w_sigma[t], W_rgb[t*3+0], W_rgb[t*3+1], W_rgb[t*3+2]);
    } else if (t < HID + 9) {
        sWd[t - HID] = W_dir[t - HID];
    } else if (t < HID + 12) {
        sWd[t - HID] = b_rgb[t - HID - 9];
    }
    __syncthreads();

    const int ray = blockIdx.x;
    const float ox = ray_start[ray*3+0], oy = ray_start[ray*3+1], oz = ray_start[ray*3+2];
    const float dx = ray_dir[ray*3+0],  dy = ray_dir[ray*3+1],  dz = ray_dir[ray*3+2];

    // dir @ W_dir + b_rgb (per-ray, uniform across the block)
    const float dwr = dx*sWd[0] + dy*sWd[3] + dz*sWd[6] + sWd[9];
    const float dwg = dx*sWd[1] + dy*sWd[4] + dz*sWd[7] + sWd[10];
    const float dwb = dx*sWd[2] + dy*sWd[5] + dz*sWd[8] + sWd[11];

    const float d = sampled_depth[(size_t)ray*NS + t];
    const float x = fmaf(dx, d, ox);
    const float y = fmaf(dy, d, oy);
    const float z = fmaf(dz, d, oz);

    float sig = 0.f, cr = 0.f, cg = 0.f, cb = 0.f;
#pragma unroll
    for (int h = 0; h < HID; ++h) {
        const float4 a = sWA[h];
        const float4 b = sWB[h];
        float hv = fmaf(a.x, x, fmaf(a.y, y, fmaf(a.z, z, a.w)));
        hv = fmaxf(hv, 0.f);                 // relu
        sig = fmaf(hv, b.x, sig);
        cr  = fmaf(hv, b.y, cr);
        cg  = fmaf(hv, b.z, cg);
        cb  = fmaf(hv, b.w, cb);
    }

    // sigmoid rgb
    const float r  = 1.f / (1.f + __expf(-(cr + dwr)));
    const float g  = 1.f / (1.f + __expf(-(cg + dwg)));
    const float bc = 1.f / (1.f + __expf(-(cb + dwb)));

    // free energy with miss mask
    float fe = fmaxf(sig, 0.f) * sampled_dists[(size_t)ray*NS + t] * 7.0f;
    if (sampled_idx[(size_t)ray*NS + t] == -1) fe = 0.f;

    // ---- exclusive scan of fe across the 256 samples of this ray ----
    const int lane = t & 63;
    const int wave = t >> 6;
    float incl = fe;
#pragma unroll
    for (int off = 1; off < 64; off <<= 1) {
        float v = __shfl_up(incl, off, 64);
        if (lane >= off) incl += v;
    }
    if (lane == 63) waveSum[wave] = incl;
    __syncthreads();
    float excl = incl - fe;
#pragma unroll
    for (int w = 0; w < 3; ++w)
        if (w < wave) excl += waveSum[w];

    const float prob = (1.f - __expf(-fe)) * __expf(-excl);

    // ---- reductions: colors (3), weighted depth, prob sum ----
    float s0 = prob, s1 = d * prob, s2 = r * prob, s3 = g * prob, s4 = bc * prob;
#pragma unroll
    for (int off = 32; off >= 1; off >>= 1) {
        s0 += __shfl_xor(s0, off, 64);
        s1 += __shfl_xor(s1, off, 64);
        s2 += __shfl_xor(s2, off, 64);
        s3 += __shfl_xor(s3, off, 64);
        s4 += __shfl_xor(s4, off, 64);
    }
    if (lane == 0) {
        red[wave][0] = s2;   // r
        red[wave][1] = s3;   // g
        red[wave][2] = s4;   // b
        red[wave][3] = s1;   // depth
        red[wave][4] = s0;   // prob sum
    }

    float* orow = out + (size_t)ray * (NS + 5);
    orow[5 + t] = prob;

    __syncthreads();
    if (t < 5) {
        float v = red[0][t] + red[1][t] + red[2][t] + red[3][t];
        if (t == 4) v = 1.f - v;             // missed
        orow[t] = v;
    }
}

extern "C" void kernel_launch(void* const* d_in, const int* in_sizes, int n_in,
                              void* d_out, int out_size, void* d_ws, size_t ws_size,
                              hipStream_t stream)
{
    vr_kernel<<<NRAYS, NS, 0, stream>>>(
        (const float*)d_in[0],   // ray_start
        (const float*)d_in[1],   // ray_dir
        (const float*)d_in[2],   // sampled_depth
        (const float*)d_in[3],   // sampled_dists
        (const int*)  d_in[4],   // sampled_idx
        (const float*)d_in[5],   // W1
        (const float*)d_in[6],   // b1
        (const float*)d_in[7],   // w_sigma
        (const float*)d_in[8],   // W_rgb
        (const float*)d_in[9],   // W_dir
        (const float*)d_in[10],  // b_rgb
        (float*)d_out);
}

// Round 2
// 118.787 us; speedup vs baseline: 1.7685x; 1.7685x over previous
//
#include <hip/hip_runtime.h>

#define NRAYS 8192
#define NS    256
#define HID   64
#define RPB   4      // rays per block, one per wave

__global__ __launch_bounds__(256) void vr_kernel(
    const float* __restrict__ ray_start,
    const float* __restrict__ ray_dir,
    const float* __restrict__ sampled_depth,
    const float* __restrict__ sampled_dists,
    const int*   __restrict__ sampled_idx,
    const float* __restrict__ W1,
    const float* __restrict__ b1,
    const float* __restrict__ w_sigma,
    const float* __restrict__ W_rgb,
    const float* __restrict__ W_dir,
    const float* __restrict__ b_rgb,
    float* __restrict__ out)
{
    // sWA[h] = {W1[0][h], W1[1][h], W1[2][h], b1[h]}
    // sWB[h] = {w_sigma[h], W_rgb[h][0], W_rgb[h][1], W_rgb[h][2]}
    __shared__ float4 sWA[HID];
    __shared__ float4 sWB[HID];
    __shared__ float  sWd[12];      // W_dir (9) + b_rgb (3)

    const int t = threadIdx.x;
    if (t < HID) {
        sWA[t] = make_float4(W1[t], W1[HID + t], W1[2*HID + t], b1[t]);
        sWB[t] = make_float4(w_sigma[t], W_rgb[t*3+0], W_rgb[t*3+1], W_rgb[t*3+2]);
    } else if (t < HID + 12) {
        sWd[t - HID] = (t < HID + 9) ? W_dir[t - HID] : b_rgb[t - HID - 9];
    }
    __syncthreads();

    const int lane = t & 63;
    const int wave = t >> 6;
    const int ray  = blockIdx.x * RPB + wave;

    const float ox = ray_start[ray*3+0], oy = ray_start[ray*3+1], oz = ray_start[ray*3+2];
    const float dx = ray_dir[ray*3+0],  dy = ray_dir[ray*3+1],  dz = ray_dir[ray*3+2];

    // per-ray view-dependent rgb bias (uniform across the wave)
    const float dwr = dx*sWd[0] + dy*sWd[3] + dz*sWd[6] + sWd[9];
    const float dwg = dx*sWd[1] + dy*sWd[4] + dz*sWd[7] + sWd[10];
    const float dwb = dx*sWd[2] + dy*sWd[5] + dz*sWd[8] + sWd[11];

    // this thread owns samples 4*lane .. 4*lane+3 (contiguous): float4/int4 loads
    const size_t rbase = (size_t)ray * NS;
    const float4 dep = ((const float4*)(sampled_depth + rbase))[lane];
    const float4 dst = ((const float4*)(sampled_dists + rbase))[lane];
    const int4   vidx = ((const int4*)(sampled_idx + rbase))[lane];

    const float dpt[4] = {dep.x, dep.y, dep.z, dep.w};
    const float dsv[4] = {dst.x, dst.y, dst.z, dst.w};
    const int   idx4[4] = {vidx.x, vidx.y, vidx.z, vidx.w};

    float X[4], Y[4], Z[4];
#pragma unroll
    for (int j = 0; j < 4; ++j) {
        X[j] = fmaf(dx, dpt[j], ox);
        Y[j] = fmaf(dy, dpt[j], oy);
        Z[j] = fmaf(dz, dpt[j], oz);
    }

    float sig[4] = {0,0,0,0};
    float cr[4]  = {0,0,0,0};
    float cg[4]  = {0,0,0,0};
    float cb[4]  = {0,0,0,0};

#pragma unroll 16
    for (int h = 0; h < HID; ++h) {
        const float4 a = sWA[h];
        const float4 b = sWB[h];
#pragma unroll
        for (int j = 0; j < 4; ++j) {
            float hv = fmaf(a.x, X[j], fmaf(a.y, Y[j], fmaf(a.z, Z[j], a.w)));
            hv = fmaxf(hv, 0.f);
            sig[j] = fmaf(hv, b.x, sig[j]);
            cr[j]  = fmaf(hv, b.y, cr[j]);
            cg[j]  = fmaf(hv, b.z, cg[j]);
            cb[j]  = fmaf(hv, b.w, cb[j]);
        }
    }

    // free energy + thread-local inclusive scan over the 4 owned samples
    float fe[4], c[4];
#pragma unroll
    for (int j = 0; j < 4; ++j) {
        float f = fmaxf(sig[j], 0.f) * dsv[j] * 7.0f;
        if (idx4[j] == -1) f = 0.f;
        fe[j] = f;
        c[j] = (j == 0) ? f : c[j-1] + f;
    }

    // wave-level exclusive scan of per-thread totals
    float tot = c[3];
#pragma unroll
    for (int off = 1; off < 64; off <<= 1) {
        float v = __shfl_up(tot, off, 64);
        if (lane >= off) tot += v;
    }
    const float base = tot - c[3];   // exclusive prefix for this thread's first sample

    // probs + rgb + partial sums
    float s0 = 0.f, s1 = 0.f, s2 = 0.f, s3 = 0.f, s4 = 0.f;
    float prob[4];
#pragma unroll
    for (int j = 0; j < 4; ++j) {
        const float excl = base + ((j == 0) ? 0.f : c[j-1]);
        const float p = (1.f - __expf(-fe[j])) * __expf(-excl);
        prob[j] = p;
        const float r = __builtin_amdgcn_rcpf(1.f + __expf(-(cr[j] + dwr)));
        const float g = __builtin_amdgcn_rcpf(1.f + __expf(-(cg[j] + dwg)));
        const float b = __builtin_amdgcn_rcpf(1.f + __expf(-(cb[j] + dwb)));
        s0 += p;
        s1 = fmaf(dpt[j], p, s1);
        s2 = fmaf(r, p, s2);
        s3 = fmaf(g, p, s3);
        s4 = fmaf(b, p, s4);
    }

    // wave reduction of the 5 sums
#pragma unroll
    for (int off = 32; off >= 1; off >>= 1) {
        s0 += __shfl_xor(s0, off, 64);
        s1 += __shfl_xor(s1, off, 64);
        s2 += __shfl_xor(s2, off, 64);
        s3 += __shfl_xor(s3, off, 64);
        s4 += __shfl_xor(s4, off, 64);
    }

    float* orow = out + (size_t)ray * (NS + 5);
    // probs: thread writes its 4 contiguous samples (region orow[5..261))
#pragma unroll
    for (int j = 0; j < 4; ++j)
        orow[5 + 4*lane + j] = prob[j];

    if (lane == 0) {
        orow[0] = s2;          // r
        orow[1] = s3;          // g
        orow[2] = s4;          // b
        orow[3] = s1;          // depth
        orow[4] = 1.f - s0;    // missed
    }
}

extern "C" void kernel_launch(void* const* d_in, const int* in_sizes, int n_in,
                              void* d_out, int out_size, void* d_ws, size_t ws_size,
                              hipStream_t stream)
{
    vr_kernel<<<NRAYS / RPB, 256, 0, stream>>>(
        (const float*)d_in[0],   // ray_start
        (const float*)d_in[1],   // ray_dir
        (const float*)d_in[2],   // sampled_depth
        (const float*)d_in[3],   // sampled_dists
        (const int*)  d_in[4],   // sampled_idx
        (const float*)d_in[5],   // W1
        (const float*)d_in[6],   // b1
        (const float*)d_in[7],   // w_sigma
        (const float*)d_in[8],   // W_rgb
        (const float*)d_in[9],   // W_dir
        (const float*)d_in[10],  // b_rgb
        (float*)d_out);
}